// Round 1
// baseline (7574.239 us; speedup 1.0000x reference)
//
#include <hip/hip_runtime.h>
#include <cstddef>

#define NT 512

namespace {
constexpr int NWIN = 72;     // tokens per window
constexpr int DIM  = 192;
constexpr int HD   = 32;     // head dim
constexpr float QSCALE = 0.17677669529663687f;  // 32^-0.5

// LDS layout (float offsets)
constexpr int Q2_OFF   = 0;                   // [72][64]  q, 2 heads
constexpr int K2T_OFF  = Q2_OFF  + 72 * 64;   // [64][73]  k transposed (stride 73 -> conflict-free)
constexpr int V2_OFF   = K2T_OFF + 64 * 73;   // [72][64]  v, 2 heads
constexpr int PO_OFF   = V2_OFF  + 72 * 64;   // [72][192] concat attention output
constexpr int UN_OFF   = PO_OFF  + 72 * 192;  // union: W-stage [32][192] | S0,S1 [72][76]
constexpr int S_STRIDE = 76;
constexpr int S1_REL   = 72 * S_STRIDE;
constexpr int LDS_FLOATS = UN_OFF + 2 * S1_REL;   // 38656 floats = 154,624 B (<160 KiB)
}

__device__ __forceinline__ float bias_val(const float* __restrict__ btab,
                                          int a, int b, int h, int w31, int tlat) {
  // bias = table[pos[((a*72+b)*60 + w/31) % 5184], w % 31, h]
  int Q  = a * NWIN + b;
  int P  = (Q * 60 + w31) % 5184;
  int p1 = P / NWIN;
  int p2 = P - p1 * NWIN;
  int i1 = p1 / 12, j1 = p1 - i1 * 12;
  int i2 = p2 / 12, j2 = p2 - i2 * 12;
  int row = (i1 + 6 * i2) * 23 + (j1 - j2 + 11);
  return btab[(row * 31 + tlat) * 6 + h];
}

__global__ __launch_bounds__(NT, 2)
void earth_attn_kernel(const float* __restrict__ x,    const float* __restrict__ mask,
                       const float* __restrict__ wqkv, const float* __restrict__ bqkv,
                       const float* __restrict__ wout, const float* __restrict__ bout,
                       const float* __restrict__ btab, float* __restrict__ out)
{
  extern __shared__ float lds[];
  float* q2  = lds + Q2_OFF;
  float* k2T = lds + K2T_OFF;
  float* v2  = lds + V2_OFF;
  float* po  = lds + PO_OFF;
  float* un  = lds + UN_OFF;

  const int w   = blockIdx.x;
  const int tid = threadIdx.x;
  const int tx  = tid & 63;   // lane within wave
  const int ty  = tid >> 6;   // wave id 0..7 (uniform per wave)

  const int mrow = w % 30;
  const int tlat = w % 31;
  const int w31  = w / 31;

  const float* xw    = x + (size_t)w * (NWIN * DIM);
  const float* maskw = mask + (size_t)mrow * (NWIN * NWIN);

  for (int pass = 0; pass < 3; ++pass) {
    const int h0 = pass * 2;

    // ---------- GEMM A: qkv (heads h0, h0+1): rows rr*8+ty, cols cc*64+tx ----------
    float a0[9], a1[9], a2[9];
    #pragma unroll
    for (int rr = 0; rr < 9; ++rr) { a0[rr] = 0.f; a1[rr] = 0.f; a2[rr] = 0.f; }

    for (int k0 = 0; k0 < DIM; k0 += 32) {
      __syncthreads();  // protect union buffer (prev pass S / prev stage W)
      #pragma unroll
      for (int i = 0; i < 12; ++i) {          // stage W chunk [32][192]
        int e  = tid + i * NT;                // 0..6143
        int kk = e / 192;
        int c  = e - kk * 192;
        int col = (c >> 6) * DIM + h0 * HD + (c & 63);  // (which)*192 + h0*32 + d2
        un[kk * 192 + c] = wqkv[(size_t)(k0 + kk) * 576 + col];
      }
      __syncthreads();
      #pragma unroll
      for (int kk0 = 0; kk0 < 32; kk0 += 4) {
        float4 xa[9];
        #pragma unroll
        for (int rr = 0; rr < 9; ++rr)
          xa[rr] = *(const float4*)(xw + (rr * 8 + ty) * DIM + k0 + kk0);
        float wv0[4], wv1[4], wv2[4];
        #pragma unroll
        for (int j = 0; j < 4; ++j) {
          wv0[j] = un[(kk0 + j) * 192 + tx];
          wv1[j] = un[(kk0 + j) * 192 + 64 + tx];
          wv2[j] = un[(kk0 + j) * 192 + 128 + tx];
        }
        #pragma unroll
        for (int rr = 0; rr < 9; ++rr) {
          a0[rr] = fmaf(xa[rr].x, wv0[0], a0[rr]);
          a0[rr] = fmaf(xa[rr].y, wv0[1], a0[rr]);
          a0[rr] = fmaf(xa[rr].z, wv0[2], a0[rr]);
          a0[rr] = fmaf(xa[rr].w, wv0[3], a0[rr]);
          a1[rr] = fmaf(xa[rr].x, wv1[0], a1[rr]);
          a1[rr] = fmaf(xa[rr].y, wv1[1], a1[rr]);
          a1[rr] = fmaf(xa[rr].z, wv1[2], a1[rr]);
          a1[rr] = fmaf(xa[rr].w, wv1[3], a1[rr]);
          a2[rr] = fmaf(xa[rr].x, wv2[0], a2[rr]);
          a2[rr] = fmaf(xa[rr].y, wv2[1], a2[rr]);
          a2[rr] = fmaf(xa[rr].z, wv2[2], a2[rr]);
          a2[rr] = fmaf(xa[rr].w, wv2[3], a2[rr]);
        }
      }
    }

    {  // epilogue: +bias, scale q, store to LDS
      float bq = bqkv[h0 * HD + tx];
      float bk = bqkv[DIM + h0 * HD + tx];
      float bv = bqkv[2 * DIM + h0 * HD + tx];
      #pragma unroll
      for (int rr = 0; rr < 9; ++rr) {
        int r = rr * 8 + ty;
        q2[r * 64 + tx]  = (a0[rr] + bq) * QSCALE;
        k2T[tx * 73 + r] = a1[rr] + bk;     // transposed store, stride 73
        v2[r * 64 + tx]  = a2[rr] + bv;
      }
    }
    __syncthreads();

    // ---------- S = q k^T, both heads; cols b = tx and 64+tx (tx<8) ----------
    float s0[9][2], s1[9][2];
    #pragma unroll
    for (int rr = 0; rr < 9; ++rr) { s0[rr][0]=0.f; s0[rr][1]=0.f; s1[rr][0]=0.f; s1[rr][1]=0.f; }
    #pragma unroll
    for (int hh = 0; hh < 2; ++hh) {
      const int off = hh * HD;
      #pragma unroll
      for (int kk0 = 0; kk0 < HD; kk0 += 4) {
        float kva[4], kvb[4];
        #pragma unroll
        for (int j = 0; j < 4; ++j) {
          kva[j] = k2T[(off + kk0 + j) * 73 + tx];
          kvb[j] = k2T[(off + kk0 + j) * 73 + 64 + tx];  // junk for tx>=8 (discarded, in-LDS)
        }
        #pragma unroll
        for (int rr = 0; rr < 9; ++rr) {
          float4 q4 = *(const float4*)(q2 + (rr * 8 + ty) * 64 + off + kk0);  // wave-broadcast
          float da = q4.x*kva[0] + q4.y*kva[1] + q4.z*kva[2] + q4.w*kva[3];
          float db = q4.x*kvb[0] + q4.y*kvb[1] + q4.z*kvb[2] + q4.w*kvb[3];
          if (hh == 0) { s0[rr][0] += da; s0[rr][1] += db; }
          else         { s1[rr][0] += da; s1[rr][1] += db; }
        }
      }
    }

    // ---------- bias + mask + softmax (row lives in one wave -> shfl reduce) ----------
    float* S0 = un;
    float* S1 = un + S1_REL;
    #pragma unroll
    for (int rr = 0; rr < 9; ++rr) {
      const int a = rr * 8 + ty;
      const float m0  = maskw[a * NWIN + tx];
      const float m1v = (tx < 8) ? maskw[a * NWIN + 64 + tx] : 0.f;
      #pragma unroll
      for (int hh = 0; hh < 2; ++hh) {
        const int h = h0 + hh;
        float v0 = (hh ? s1[rr][0] : s0[rr][0]) + bias_val(btab, a, tx, h, w31, tlat) + m0;
        float v1 = -1e30f;
        if (tx < 8)
          v1 = (hh ? s1[rr][1] : s0[rr][1]) + bias_val(btab, a, 64 + tx, h, w31, tlat) + m1v;
        float mx = fmaxf(v0, v1);
        #pragma unroll
        for (int o = 32; o > 0; o >>= 1) mx = fmaxf(mx, __shfl_xor(mx, o));
        float e0 = __expf(v0 - mx);
        float e1 = (tx < 8) ? __expf(v1 - mx) : 0.f;
        float sm = e0 + e1;
        #pragma unroll
        for (int o = 32; o > 0; o >>= 1) sm += __shfl_xor(sm, o);
        float inv = 1.0f / sm;
        float* Sh = hh ? S1 : S0;
        Sh[a * S_STRIDE + tx] = e0 * inv;
        if (tx < 8) Sh[a * S_STRIDE + 64 + tx] = e1 * inv;
      }
    }

    // ---------- PV: out col = pass*64 + tx (head = tx/32). Same-wave S dep: no barrier ----------
    {
      const float* Sh = (tx < 32) ? S0 : S1;
      float o[9];
      #pragma unroll
      for (int rr = 0; rr < 9; ++rr) o[rr] = 0.f;
      for (int b0 = 0; b0 < NWIN; b0 += 4) {
        float vv[4];
        #pragma unroll
        for (int j = 0; j < 4; ++j) vv[j] = v2[(b0 + j) * 64 + tx];
        #pragma unroll
        for (int rr = 0; rr < 9; ++rr) {
          float4 p4 = *(const float4*)(Sh + (rr * 8 + ty) * S_STRIDE + b0);
          o[rr] += p4.x*vv[0] + p4.y*vv[1] + p4.z*vv[2] + p4.w*vv[3];
        }
      }
      #pragma unroll
      for (int rr = 0; rr < 9; ++rr)
        po[(rr * 8 + ty) * DIM + pass * 64 + tx] = o[rr];
    }
  }  // pass

  // ---------- out projection: y = po @ w_out + b_out ----------
  float c0[9], c1[9], c2[9];
  #pragma unroll
  for (int rr = 0; rr < 9; ++rr) { c0[rr] = 0.f; c1[rr] = 0.f; c2[rr] = 0.f; }
  for (int k0 = 0; k0 < DIM; k0 += 32) {
    __syncthreads();  // protect union (last used as S by PV)
    #pragma unroll
    for (int i = 0; i < 12; ++i) {
      int e  = tid + i * NT;
      int kk = e / 192;
      int c  = e - kk * 192;
      un[kk * 192 + c] = wout[(size_t)(k0 + kk) * DIM + c];
    }
    __syncthreads();
    #pragma unroll
    for (int kk0 = 0; kk0 < 32; kk0 += 4) {
      float4 pa[9];
      #pragma unroll
      for (int rr = 0; rr < 9; ++rr)
        pa[rr] = *(const float4*)(po + (rr * 8 + ty) * DIM + k0 + kk0);
      float wv0[4], wv1[4], wv2[4];
      #pragma unroll
      for (int j = 0; j < 4; ++j) {
        wv0[j] = un[(kk0 + j) * 192 + tx];
        wv1[j] = un[(kk0 + j) * 192 + 64 + tx];
        wv2[j] = un[(kk0 + j) * 192 + 128 + tx];
      }
      #pragma unroll
      for (int rr = 0; rr < 9; ++rr) {
        c0[rr] = fmaf(pa[rr].x, wv0[0], c0[rr]);
        c0[rr] = fmaf(pa[rr].y, wv0[1], c0[rr]);
        c0[rr] = fmaf(pa[rr].z, wv0[2], c0[rr]);
        c0[rr] = fmaf(pa[rr].w, wv0[3], c0[rr]);
        c1[rr] = fmaf(pa[rr].x, wv1[0], c1[rr]);
        c1[rr] = fmaf(pa[rr].y, wv1[1], c1[rr]);
        c1[rr] = fmaf(pa[rr].z, wv1[2], c1[rr]);
        c1[rr] = fmaf(pa[rr].w, wv1[3], c1[rr]);
        c2[rr] = fmaf(pa[rr].x, wv2[0], c2[rr]);
        c2[rr] = fmaf(pa[rr].y, wv2[1], c2[rr]);
        c2[rr] = fmaf(pa[rr].z, wv2[2], c2[rr]);
        c2[rr] = fmaf(pa[rr].w, wv2[3], c2[rr]);
      }
    }
  }
  {
    const float b0v = bout[tx];
    const float b1v = bout[64 + tx];
    const float b2v = bout[128 + tx];
    float* ow = out + (size_t)w * (NWIN * DIM);
    #pragma unroll
    for (int rr = 0; rr < 9; ++rr) {
      int r = rr * 8 + ty;
      ow[r * DIM + tx]       = c0[rr] + b0v;
      ow[r * DIM + 64 + tx]  = c1[rr] + b1v;
      ow[r * DIM + 128 + tx] = c2[rr] + b2v;
    }
  }
}

extern "C" void kernel_launch(void* const* d_in, const int* in_sizes, int n_in,
                              void* d_out, int out_size, void* d_ws, size_t ws_size,
                              hipStream_t stream) {
  const float* x    = (const float*)d_in[0];
  const float* mask = (const float*)d_in[1];
  const float* wqkv = (const float*)d_in[2];
  const float* bqkv = (const float*)d_in[3];
  const float* wout = (const float*)d_in[4];
  const float* bout = (const float*)d_in[5];
  const float* btab = (const float*)d_in[6];
  float* out = (float*)d_out;

  const int nwindows = in_sizes[0] / (NWIN * DIM);   // 1860
  const size_t ldsB = (size_t)LDS_FLOATS * sizeof(float);  // 154,624 B

  // Defensive: allow >48KB dynamic LDS if the runtime validates against an attribute.
  // Idempotent host call (not a stream op) -> safe under graph capture; ignore result.
  (void)hipFuncSetAttribute((const void*)earth_attn_kernel,
                            hipFuncAttributeMaxDynamicSharedMemorySize, (int)ldsB);

  hipLaunchKernelGGL(earth_attn_kernel, dim3(nwindows), dim3(NT), ldsB, stream,
                     x, mask, wqkv, bqkv, wout, bout, btab, out);
}